// Round 2
// baseline (271.028 us; speedup 1.0000x reference)
//
#include <hip/hip_runtime.h>
#include <hip/hip_bf16.h>
#include <stdint.h>

#define L_ 4
#define B_ 128
#define H_ 4096
#define BK 64
#define BN 32
#define KSTEPS 256            // L_*H_/BK
#define NTHR 256
#define ABYTES (128*BK*2)     // 16384 B : A tile 128 x 64 fp16
#define WBYTES (BN*BK*2)      // 4096 B  : W tile 32 x 64 fp16
#define BUFBYTES (ABYTES+WBYTES)

typedef _Float16 f16x8 __attribute__((ext_vector_type(8)));
typedef float    f32x4 __attribute__((ext_vector_type(4)));
typedef float    f4    __attribute__((ext_vector_type(4)));
typedef uint32_t u32x4 __attribute__((ext_vector_type(4)));
typedef uint32_t u32x2 __attribute__((ext_vector_type(2)));

// RNE f32 -> fp16 pair packed into u32 (v_cvt_f16_f32 is round-nearest-even)
__device__ __forceinline__ uint32_t pack2(float a, float b) {
  const _Float16 ha = (_Float16)a;
  const _Float16 hb = (_Float16)b;
  const uint32_t ua = (uint32_t)__builtin_bit_cast(uint16_t, ha);
  const uint32_t ub = (uint32_t)__builtin_bit_cast(uint16_t, hb);
  return ua | (ub << 16);
}

__global__ void cvt_states_kernel(const float* __restrict__ x,
                                  uint32_t* __restrict__ y, int n4) {
  const int i = blockIdx.x * blockDim.x + threadIdx.x;
  if (i < n4) {
    f4 v = reinterpret_cast<const f4*>(x)[i];
    u32x2 o;
    o.x = pack2(v.x, v.y);
    o.y = pack2(v.z, v.w);
    reinterpret_cast<u32x2*>(y)[i] = o;
  }
}

template<bool USE_WS>
__global__ __launch_bounds__(NTHR, 2)
void net_gemm_kernel(const float* __restrict__ statesf,
                     const uint16_t* __restrict__ statesh,
                     const float* __restrict__ Wm,
                     const float* __restrict__ ext,
                     float* __restrict__ out)
{
  __shared__ uint8_t lds[2 * BUFBYTES];   // 40 KB, double-buffered

  const int tid  = threadIdx.x;
  const int bid  = blockIdx.x;
  const int t    = bid >> 7;              // 0..3
  const int n0   = (bid & 127) * BN;      // output-col tile

  const int wv   = tid >> 6;              // wave 0..3
  const int lane = tid & 63;
  const int lid  = lane & 15;
  const int lh   = lane >> 4;

  // ---- A staging map: thread -> (row group j*32+arow, 8 elems at acol) ----
  const int arow = tid >> 3;              // 0..31
  const int acol = (tid & 7) * 8;
  const uint32_t a_st_off =
      (uint32_t)arow * 128 + (((uint32_t)(tid & 7) * 16) ^ ((uint32_t)(arow & 7) << 4));
  const uint16_t* ah_base = USE_WS ? (statesh + (size_t)arow * H_ + acol) : nullptr;
  const float*    af_base = statesf + (size_t)arow * H_ + acol;

  // ---- W staging map: 2 pieces/thread, each 4 f32, full-row contiguity/instr ----
  const int wrow = tid >> 4;              // 0..15 (second piece = +16)
  const int wcol = (tid & 15) * 4;
  const float* w_base = Wm + ((size_t)t * L_ * H_ + (size_t)(n0 + wrow)) * H_ + wcol;
  const uint32_t w_st_off0 =
      (uint32_t)ABYTES + (uint32_t)wrow * 128 + (((uint32_t)(tid & 15) * 8) ^ ((uint32_t)(wrow & 7) << 4));
  const uint32_t w_st_off1 = w_st_off0 + 16 * 128;

  // ---- LDS read offsets for MFMA fragments (constant per thread) ----
  uint32_t a_rd[2][2], b_rd[2][2];
  #pragma unroll
  for (int mf = 0; mf < 2; ++mf)
    #pragma unroll
    for (int kk = 0; kk < 2; ++kk) {
      const int row = wv * 32 + mf * 16 + lid;
      a_rd[mf][kk] = (uint32_t)row * 128 +
                     (((uint32_t)(kk * 64 + lh * 16)) ^ ((uint32_t)(lid & 7) << 4));
    }
  #pragma unroll
  for (int nf = 0; nf < 2; ++nf)
    #pragma unroll
    for (int kk = 0; kk < 2; ++kk) {
      const int row = nf * 16 + lid;
      b_rd[nf][kk] = (uint32_t)ABYTES + (uint32_t)row * 128 +
                     (((uint32_t)(kk * 64 + lh * 16)) ^ ((uint32_t)(lid & 7) << 4));
    }

  f32x4 acc[2][2] = {};

  u32x4 a_h[4];
  f4    a_f[4][2];
  f4    w_f[2];

  auto LOAD = [&](int kidx) {
    const int s  = kidx >> 6;
    const int h0 = (kidx & 63) << 6;
    if (USE_WS) {
      const uint16_t* ap = ah_base + (size_t)s * (B_ * H_) + h0;
      #pragma unroll
      for (int j = 0; j < 4; ++j)
        a_h[j] = *reinterpret_cast<const u32x4*>(ap + (size_t)j * (32 * H_));
    } else {
      const float* ap = af_base + (size_t)s * (B_ * H_) + h0;
      #pragma unroll
      for (int j = 0; j < 4; ++j) {
        a_f[j][0] = *reinterpret_cast<const f4*>(ap + (size_t)j * (32 * H_));
        a_f[j][1] = *reinterpret_cast<const f4*>(ap + (size_t)j * (32 * H_) + 4);
      }
    }
    const float* wp = w_base + (size_t)s * ((size_t)H_ * H_) + h0;
    w_f[0] = __builtin_nontemporal_load(reinterpret_cast<const f4*>(wp));
    w_f[1] = __builtin_nontemporal_load(reinterpret_cast<const f4*>(wp + 16 * (size_t)H_));
  };

  auto WRITE = [&](int p) {
    uint8_t* base = lds + p * BUFBYTES;
    if (USE_WS) {
      #pragma unroll
      for (int j = 0; j < 4; ++j)
        *reinterpret_cast<u32x4*>(base + j * 4096 + a_st_off) = a_h[j];
    } else {
      #pragma unroll
      for (int j = 0; j < 4; ++j) {
        u32x4 v;
        v.x = pack2(a_f[j][0].x, a_f[j][0].y);
        v.y = pack2(a_f[j][0].z, a_f[j][0].w);
        v.z = pack2(a_f[j][1].x, a_f[j][1].y);
        v.w = pack2(a_f[j][1].z, a_f[j][1].w);
        *reinterpret_cast<u32x4*>(base + j * 4096 + a_st_off) = v;
      }
    }
    u32x2 w0, w1;
    w0.x = pack2(w_f[0].x, w_f[0].y); w0.y = pack2(w_f[0].z, w_f[0].w);
    w1.x = pack2(w_f[1].x, w_f[1].y); w1.y = pack2(w_f[1].z, w_f[1].w);
    *reinterpret_cast<u32x2*>(base + w_st_off0) = w0;
    *reinterpret_cast<u32x2*>(base + w_st_off1) = w1;
  };

  auto COMPUTE = [&](int p) {
    const uint8_t* base = lds + p * BUFBYTES;
    f16x8 av[2][2], bv[2][2];
    #pragma unroll
    for (int mf = 0; mf < 2; ++mf)
      #pragma unroll
      for (int kk = 0; kk < 2; ++kk)
        av[mf][kk] = *reinterpret_cast<const f16x8*>(base + a_rd[mf][kk]);
    #pragma unroll
    for (int nf = 0; nf < 2; ++nf)
      #pragma unroll
      for (int kk = 0; kk < 2; ++kk)
        bv[nf][kk] = *reinterpret_cast<const f16x8*>(base + b_rd[nf][kk]);
    #pragma unroll
    for (int kk = 0; kk < 2; ++kk)
      #pragma unroll
      for (int mf = 0; mf < 2; ++mf)
        #pragma unroll
        for (int nf = 0; nf < 2; ++nf)
          acc[mf][nf] = __builtin_amdgcn_mfma_f32_16x16x32_f16(
              av[mf][kk], bv[nf][kk], acc[mf][nf], 0, 0, 0);
  };

  LOAD(0);
  WRITE(0);
  __syncthreads();

  for (int k = 0; k < KSTEPS; ++k) {
    const int p = k & 1;
    if (k + 1 < KSTEPS) LOAD(k + 1);    // issue next-tile global loads early
    COMPUTE(p);
    if (k + 1 < KSTEPS) {
      WRITE(p ^ 1);                     // vmcnt wait happens here (first use)
      __syncthreads();
    }
  }

  // ---- epilogue: out = tanh(acc + ext), C/D layout col=lane&15, row=lh*4+j ----
  #pragma unroll
  for (int mf = 0; mf < 2; ++mf)
    #pragma unroll
    for (int nf = 0; nf < 2; ++nf)
      #pragma unroll
      for (int j = 0; j < 4; ++j) {
        const int brow = wv * 32 + mf * 16 + lh * 4 + j;
        const int ocol = n0 + nf * 16 + lid;
        const size_t idx = ((size_t)(t * B_ + brow)) * H_ + ocol;
        out[idx] = tanhf(acc[mf][nf][j] + ext[idx]);
      }
}

extern "C" void kernel_launch(void* const* d_in, const int* in_sizes, int n_in,
                              void* d_out, int out_size, void* d_ws, size_t ws_size,
                              hipStream_t stream) {
  const float* states = (const float*)d_in[0];
  const float* W      = (const float*)d_in[1];
  const float* ext    = (const float*)d_in[2];
  float* out          = (float*)d_out;

  const size_t nstates = (size_t)L_ * B_ * H_;       // 2,097,152 elements
  if (ws_size >= nstates * sizeof(uint16_t)) {
    const int n4 = (int)(nstates / 4);
    cvt_states_kernel<<<(n4 + 255) / 256, 256, 0, stream>>>(states, (uint32_t*)d_ws, n4);
    net_gemm_kernel<true><<<512, NTHR, 0, stream>>>(
        states, (const uint16_t*)d_ws, W, ext, out);
  } else {
    net_gemm_kernel<false><<<512, NTHR, 0, stream>>>(
        states, nullptr, W, ext, out);
  }
}

// Round 3
// 250.765 us; speedup vs baseline: 1.0808x; 1.0808x over previous
//
#include <hip/hip_runtime.h>
#include <hip/hip_bf16.h>
#include <stdint.h>

#define L_ 4
#define B_ 128
#define H_ 4096
#define BK 64
#define BN 32
#define KSTEPS 256            // L_*H_/BK
#define NTHR 256
#define ABYTES (128*BK*2)     // 16384 B : A tile 128 x 64 fp16
#define WBYTES (BN*BK*2)      // 4096 B  : W tile 32 x 64 fp16
#define BUFBYTES (ABYTES+WBYTES)

typedef _Float16 f16x8 __attribute__((ext_vector_type(8)));
typedef float    f32x4 __attribute__((ext_vector_type(4)));
typedef float    f4    __attribute__((ext_vector_type(4)));
typedef uint32_t u32x4 __attribute__((ext_vector_type(4)));
typedef uint32_t u32x2 __attribute__((ext_vector_type(2)));

// RNE f32 -> fp16 pair packed into u32 (v_cvt_f16_f32 is round-nearest-even)
__device__ __forceinline__ uint32_t pack2(float a, float b) {
  const _Float16 ha = (_Float16)a;
  const _Float16 hb = (_Float16)b;
  const uint32_t ua = (uint32_t)__builtin_bit_cast(uint16_t, ha);
  const uint32_t ub = (uint32_t)__builtin_bit_cast(uint16_t, hb);
  return ua | (ub << 16);
}

__global__ void cvt_states_kernel(const float* __restrict__ x,
                                  uint32_t* __restrict__ y, int n4) {
  const int i = blockIdx.x * blockDim.x + threadIdx.x;
  if (i < n4) {
    f4 v = reinterpret_cast<const f4*>(x)[i];
    u32x2 o;
    o.x = pack2(v.x, v.y);
    o.y = pack2(v.z, v.w);
    reinterpret_cast<u32x2*>(y)[i] = o;
  }
}

// counted-wait barrier: own ds ops complete, global loads stay in flight.
__device__ __forceinline__ void bar_lgkm0() {
  __builtin_amdgcn_sched_barrier(0);
  asm volatile("s_waitcnt lgkmcnt(0)");
  __builtin_amdgcn_sched_barrier(0);
  __builtin_amdgcn_s_barrier();
  __builtin_amdgcn_sched_barrier(0);
}

template<bool USE_WS>
__global__ __launch_bounds__(NTHR, 2)
void net_gemm_kernel(const float* __restrict__ statesf,
                     const uint16_t* __restrict__ statesh,
                     const float* __restrict__ Wm,
                     const float* __restrict__ ext,
                     float* __restrict__ out)
{
  __shared__ uint8_t lds[2 * BUFBYTES];   // 40 KB, double-buffered

  const int tid  = threadIdx.x;
  const int bid  = blockIdx.x;
  const int t    = bid >> 7;              // 0..3
  const int n0   = (bid & 127) * BN;      // output-col tile

  const int wv   = tid >> 6;              // wave 0..3
  const int lane = tid & 63;
  const int lid  = lane & 15;
  const int lh   = lane >> 4;

  // ---- A staging map: thread -> (row group j*32+arow, 8 elems at acol) ----
  const int arow = tid >> 3;              // 0..31
  const int acol = (tid & 7) * 8;
  const uint32_t a_st_off =
      (uint32_t)arow * 128 + (((uint32_t)(tid & 7) * 16) ^ ((uint32_t)(arow & 7) << 4));
  const uint16_t* ah_base = USE_WS ? (statesh + (size_t)arow * H_ + acol) : nullptr;
  const float*    af_base = statesf + (size_t)arow * H_ + acol;

  // ---- W staging map: 2 pieces/thread, each 4 f32 ----
  const int wrow = tid >> 4;              // 0..15 (second piece = +16)
  const int wcol = (tid & 15) * 4;
  const float* w_base = Wm + ((size_t)t * L_ * H_ + (size_t)(n0 + wrow)) * H_ + wcol;
  const uint32_t w_st_off0 =
      (uint32_t)ABYTES + (uint32_t)wrow * 128 + (((uint32_t)(tid & 15) * 8) ^ ((uint32_t)(wrow & 7) << 4));
  const uint32_t w_st_off1 = w_st_off0 + 16 * 128;

  // ---- LDS read offsets for MFMA fragments (constant per thread) ----
  uint32_t a_rd[2][2], b_rd[2][2];
  #pragma unroll
  for (int mf = 0; mf < 2; ++mf)
    #pragma unroll
    for (int kk = 0; kk < 2; ++kk) {
      const int row = wv * 32 + mf * 16 + lid;
      a_rd[mf][kk] = (uint32_t)row * 128 +
                     (((uint32_t)(kk * 64 + lh * 16)) ^ ((uint32_t)(lid & 7) << 4));
    }
  #pragma unroll
  for (int nf = 0; nf < 2; ++nf)
    #pragma unroll
    for (int kk = 0; kk < 2; ++kk) {
      const int row = nf * 16 + lid;
      b_rd[nf][kk] = (uint32_t)ABYTES + (uint32_t)row * 128 +
                     (((uint32_t)(kk * 64 + lh * 16)) ^ ((uint32_t)(lid & 7) << 4));
    }

  f32x4 acc[2][2] = {};

  // two explicit register staging sets (static indexing only — rule #20)
  u32x4 ah0[4], ah1[4];
  f4    af0[4][2], af1[4][2];
  f4    wf0[2], wf1[2];

  auto LOADg = [&](int kidx, u32x4 (&ah)[4], f4 (&af)[4][2], f4 (&wf)[2]) {
    const int s  = kidx >> 6;
    const int h0 = (kidx & 63) << 6;
    if constexpr (USE_WS) {
      const uint16_t* ap = ah_base + (size_t)s * (B_ * H_) + h0;
      #pragma unroll
      for (int j = 0; j < 4; ++j)
        ah[j] = *reinterpret_cast<const u32x4*>(ap + (size_t)j * (32 * H_));
    } else {
      const float* ap = af_base + (size_t)s * (B_ * H_) + h0;
      #pragma unroll
      for (int j = 0; j < 4; ++j) {
        af[j][0] = *reinterpret_cast<const f4*>(ap + (size_t)j * (32 * H_));
        af[j][1] = *reinterpret_cast<const f4*>(ap + (size_t)j * (32 * H_) + 4);
      }
    }
    const float* wp = Wm == nullptr ? nullptr : (w_base + (size_t)s * ((size_t)H_ * H_) + h0);
    wf[0] = __builtin_nontemporal_load(reinterpret_cast<const f4*>(wp));
    wf[1] = __builtin_nontemporal_load(reinterpret_cast<const f4*>(wp + 16 * (size_t)H_));
  };

  auto WRITEg = [&](uint8_t* base, u32x4 (&ah)[4], f4 (&af)[4][2], f4 (&wf)[2]) {
    if constexpr (USE_WS) {
      #pragma unroll
      for (int j = 0; j < 4; ++j)
        *reinterpret_cast<u32x4*>(base + j * 4096 + a_st_off) = ah[j];
    } else {
      #pragma unroll
      for (int j = 0; j < 4; ++j) {
        u32x4 v;
        v.x = pack2(af[j][0].x, af[j][0].y);
        v.y = pack2(af[j][0].z, af[j][0].w);
        v.z = pack2(af[j][1].x, af[j][1].y);
        v.w = pack2(af[j][1].z, af[j][1].w);
        *reinterpret_cast<u32x4*>(base + j * 4096 + a_st_off) = v;
      }
    }
    u32x2 w0, w1;
    w0.x = pack2(wf[0].x, wf[0].y); w0.y = pack2(wf[0].z, wf[0].w);
    w1.x = pack2(wf[1].x, wf[1].y); w1.y = pack2(wf[1].z, wf[1].w);
    *reinterpret_cast<u32x2*>(base + w_st_off0) = w0;
    *reinterpret_cast<u32x2*>(base + w_st_off1) = w1;
  };

  auto COMPUTE = [&](const uint8_t* base) {
    f16x8 av[2][2], bv[2][2];
    #pragma unroll
    for (int mf = 0; mf < 2; ++mf)
      #pragma unroll
      for (int kk = 0; kk < 2; ++kk)
        av[mf][kk] = *reinterpret_cast<const f16x8*>(base + a_rd[mf][kk]);
    #pragma unroll
    for (int nf = 0; nf < 2; ++nf)
      #pragma unroll
      for (int kk = 0; kk < 2; ++kk)
        bv[nf][kk] = *reinterpret_cast<const f16x8*>(base + b_rd[nf][kk]);
    #pragma unroll
    for (int kk = 0; kk < 2; ++kk)
      #pragma unroll
      for (int mf = 0; mf < 2; ++mf)
        #pragma unroll
        for (int nf = 0; nf < 2; ++nf)
          acc[mf][nf] = __builtin_amdgcn_mfma_f32_16x16x32_f16(
              av[mf][kk], bv[nf][kk], acc[mf][nf], 0, 0, 0);
  };

  uint8_t* buf0 = lds;
  uint8_t* buf1 = lds + BUFBYTES;

  // prologue: tiles 0 and 1 in flight; write tile 0
  LOADg(0, ah0, af0, wf0);
  LOADg(1, ah1, af1, wf1);
  WRITEg(buf0, ah0, af0, wf0);   // compiler waits counted vmcnt (set1 stays in flight)
  bar_lgkm0();

  #pragma unroll 1
  for (int k = 0; k < KSTEPS; k += 2) {
    // even iter: compute tile k (buf0), write tile k+1 (buf1), prefetch k+2
    if (k + 2 < KSTEPS) LOADg(k + 2, ah0, af0, wf0);
    COMPUTE(buf0);
    WRITEg(buf1, ah1, af1, wf1);
    bar_lgkm0();

    // odd iter: compute tile k+1 (buf1), write tile k+2 (buf0), prefetch k+3
    if (k + 3 < KSTEPS) LOADg(k + 3, ah1, af1, wf1);
    COMPUTE(buf1);
    if (k + 2 < KSTEPS) {
      WRITEg(buf0, ah0, af0, wf0);
      bar_lgkm0();
    }
  }

  // ---- epilogue: out = tanh(acc + ext), C/D layout col=lane&15, row=lh*4+j ----
  #pragma unroll
  for (int mf = 0; mf < 2; ++mf)
    #pragma unroll
    for (int nf = 0; nf < 2; ++nf)
      #pragma unroll
      for (int j = 0; j < 4; ++j) {
        const int brow = wv * 32 + mf * 16 + lh * 4 + j;
        const int ocol = n0 + nf * 16 + lid;
        const size_t idx = ((size_t)(t * B_ + brow)) * H_ + ocol;
        out[idx] = tanhf(acc[mf][nf][j] + ext[idx]);
      }
}

extern "C" void kernel_launch(void* const* d_in, const int* in_sizes, int n_in,
                              void* d_out, int out_size, void* d_ws, size_t ws_size,
                              hipStream_t stream) {
  const float* states = (const float*)d_in[0];
  const float* W      = (const float*)d_in[1];
  const float* ext    = (const float*)d_in[2];
  float* out          = (float*)d_out;

  const size_t nstates = (size_t)L_ * B_ * H_;       // 2,097,152 elements
  if (ws_size >= nstates * sizeof(uint16_t)) {
    const int n4 = (int)(nstates / 4);
    cvt_states_kernel<<<(n4 + 255) / 256, 256, 0, stream>>>(states, (uint32_t*)d_ws, n4);
    net_gemm_kernel<true><<<512, NTHR, 0, stream>>>(
        states, (const uint16_t*)d_ws, W, ext, out);
  } else {
    net_gemm_kernel<false><<<512, NTHR, 0, stream>>>(
        states, nullptr, W, ext, out);
  }
}